// Round 1
// baseline (168.685 us; speedup 1.0000x reference)
//
#include <hip/hip_runtime.h>
#include <hip/hip_bf16.h>

// AxialAtten: B=4, H=W=C=64.  Two passes (height-axis, width-axis), each:
//   Q = X*Wq^T + bq ; K = Q ; V = X*Wv^T + bv
//   O = sigmoid(Q K^T / 8) V ;  x = O*scale + x   (with layout transpose)
// Pass 1 seq layout: xh[b,n,d] = x_flat[b*262144 + d*4096 + n]          (n = w*64+c, d = h)
// Pass 2 seq layout: xw[b,n,d] = x_flat[b*262144 + (n>>6)*4096 + d*64 + (n&63)]  (d = w)

typedef __attribute__((ext_vector_type(8))) short  short8;   // 8 x bf16 payload (4 VGPRs)
typedef __attribute__((ext_vector_type(4))) float  f32x4;
typedef __attribute__((ext_vector_type(2))) unsigned int u32x2;

#define BHWC (4096 * 64)   // per-batch element count

__device__ __forceinline__ unsigned short f2bf(float f) {
    union { float f; unsigned int u; } c; c.f = f;
    unsigned int r = (c.u + 0x7FFFu + ((c.u >> 16) & 1u)) >> 16;   // RNE
    return (unsigned short)r;
}

__device__ __forceinline__ float sigm(float s) {
    // sigmoid(s/8)
    float e = __expf(-0.125f * s);
    return __builtin_amdgcn_rcpf(1.0f + e);
}

// ---------------------------------------------------------------------------
// Projection: Q[b][n][o] (bf16) and V^T[b][o][n] (bf16) from fp32 x.
// MODE 0: height pass (x gather = x[b, d*4096 + n]); MODE 1: width pass.
// grid 256 = 4 batches x 64 n-tiles, block 256.
// ---------------------------------------------------------------------------
template<int MODE>
__global__ __launch_bounds__(256) void proj_kernel(
    const float* __restrict__ xsrc,
    const float* __restrict__ Wq, const float* __restrict__ Bq,
    const float* __restrict__ Wv, const float* __restrict__ Bv,
    unsigned short* __restrict__ Qo, unsigned short* __restrict__ VTo)
{
    __shared__ float xs[64][68];    // [n-local][d], pad 68 keeps 16B align + spreads banks
    __shared__ float wqs[64][68];   // [o][d]
    __shared__ float wvs[64][68];

    const int b    = blockIdx.x >> 6;
    const int tile = blockIdx.x & 63;
    const int n0   = tile << 6;
    const int tid  = threadIdx.x;
    const float* xb = xsrc + b * BHWC;

    for (int i = tid; i < 4096; i += 256) {
        const int hi = i >> 6, lo = i & 63;
        float v;
        if (MODE == 0) v = xb[hi * 4096 + n0 + lo];        // x[b, d=hi, n=n0+lo]
        else           v = xb[tile * 4096 + hi * 64 + lo]; // x[b, h=tile, w=hi, c=lo]
        xs[lo][hi]  = v;        // xs[n-local][d]
        wqs[hi][lo] = Wq[i];    // wqs[o][d]
        wvs[hi][lo] = Wv[i];
    }
    __syncthreads();

    const int o = tid & 63;     // output feature (lane-contiguous -> coalesced Q writes)
    const int g = tid >> 6;     // row group: rows g*16 .. g*16+15
    float aq[16], av[16];
    const float bq0 = Bq[o], bv0 = Bv[o];
    #pragma unroll
    for (int rr = 0; rr < 16; ++rr) { aq[rr] = bq0; av[rr] = bv0; }

    #pragma unroll
    for (int dc = 0; dc < 4; ++dc) {
        f32x4 wq4[4], wv4[4];
        #pragma unroll
        for (int q = 0; q < 4; ++q) {
            wq4[q] = *(const f32x4*)&wqs[o][dc * 16 + q * 4];
            wv4[q] = *(const f32x4*)&wvs[o][dc * 16 + q * 4];
        }
        #pragma unroll
        for (int rr = 0; rr < 16; ++rr) {
            const int r = g * 16 + rr;
            #pragma unroll
            for (int q = 0; q < 4; ++q) {
                const f32x4 xv = *(const f32x4*)&xs[r][dc * 16 + q * 4];
                aq[rr] += xv[0]*wq4[q][0] + xv[1]*wq4[q][1] + xv[2]*wq4[q][2] + xv[3]*wq4[q][3];
                av[rr] += xv[0]*wv4[q][0] + xv[1]*wv4[q][1] + xv[2]*wv4[q][2] + xv[3]*wv4[q][3];
            }
        }
    }

    unsigned short* Qb  = Qo  + b * BHWC;
    unsigned short* VTb = VTo + b * BHWC;
    #pragma unroll
    for (int rr = 0; rr < 16; ++rr) {
        const int n = n0 + g * 16 + rr;
        Qb[n * 64 + o]    = f2bf(aq[rr]);   // Q[b][n][o], coalesced over lanes
        VTb[o * 4096 + n] = f2bf(av[rr]);   // V^T[b][o][n], scattered u16 (L2 merges)
    }
}

// ---------------------------------------------------------------------------
// Fused sigmoid-attention + residual writeback.
// grid 256 = 4 batches x 64 q-tiles(64 rows), block 256 (4 waves x 16 q-rows).
// Per k-tile(64): S^T = mfma(K,Q) -> sigmoid -> P to swizzled LDS -> PV mfma.
// Double-buffered K/V staging, one barrier per iteration.
// ---------------------------------------------------------------------------
template<int MODE>
__global__ __launch_bounds__(256) void attn_kernel(
    const unsigned short* __restrict__ Q,    // [b][4096][64] bf16
    const unsigned short* __restrict__ VT,   // [b][64][4096] bf16
    const float* __restrict__ xres,
    const float* __restrict__ wsc,           // scalar weight
    float* __restrict__ xout)
{
    __shared__ unsigned short Ks[2][64 * 64];   // K tile [krow][d], XOR-swizzled rows
    __shared__ unsigned short Vs[2][64 * 64];   // V^T tile [d][klocal], XOR-swizzled
    __shared__ unsigned short Ps[64 * 64];      // P [m-local][kcol], XOR-swizzled

    const int b    = blockIdx.x >> 6;
    const int m0   = (blockIdx.x & 63) << 6;
    const int tid  = threadIdx.x;
    const int wave = tid >> 6;
    const int lane = tid & 63;
    const int lhi  = lane >> 4;    // 0..3
    const int llo  = lane & 15;

    const unsigned short* Qb  = Q  + b * BHWC;
    const unsigned short* VTb = VT + b * BHWC;

    // Hoist Q B-fragments for this wave's 16 m-rows (B[col=m-local][k=d])
    short8 qf0, qf1;
    {
        const int row = m0 + wave * 16 + llo;
        qf0 = *(const short8*)(Qb + row * 64 + lhi * 8);
        qf1 = *(const short8*)(Qb + row * 64 + lhi * 8 + 32);
    }

    f32x4 oacc[4];
    #pragma unroll
    for (int f = 0; f < 4; ++f) oacc[f] = 0.0f;

    // staging: thread owns 16B chunks tid and tid+256 of each 8KB tile
    const int r0 = tid >> 3,          c0 = tid & 7;
    const int r1 = (tid + 256) >> 3,  c1 = (tid + 256) & 7;
    const int w0 = (r0 * 128 + ((c0 * 16) ^ ((r0 & 7) << 4))) >> 1;   // short index
    const int w1 = (r1 * 128 + ((c1 * 16) ^ ((r1 & 7) << 4))) >> 1;

    short8 kreg0, kreg1, vreg0, vreg1;
    auto LOADT = [&](int kt) {
        const unsigned short* ks = Qb  + kt * 64 * 64;  // K rows = Q rows kt*64..
        const unsigned short* vs = VTb + kt * 64;
        kreg0 = *(const short8*)(ks + r0 * 64 + c0 * 8);
        kreg1 = *(const short8*)(ks + r1 * 64 + c1 * 8);
        vreg0 = *(const short8*)(vs + r0 * 4096 + c0 * 8);
        vreg1 = *(const short8*)(vs + r1 * 4096 + c1 * 8);
    };
    auto WRITET = [&](int buf) {
        *(short8*)(&Ks[buf][w0]) = kreg0;
        *(short8*)(&Ks[buf][w1]) = kreg1;
        *(short8*)(&Vs[buf][w0]) = vreg0;
        *(short8*)(&Vs[buf][w1]) = vreg1;
    };

    LOADT(0);
    WRITET(0);
    __syncthreads();

    const int m     = wave * 16 + llo;   // P row this lane owns
    const int pbase = m * 128;
    const int psw   = (m & 7) << 4;

    int cur = 0;
    for (int kt = 0; kt < 64; ++kt) {
        if (kt + 1 < 64) LOADT(kt + 1);   // async issue, hidden under compute

        const unsigned short* K_ = Ks[cur];
        const unsigned short* V_ = Vs[cur];

        // ---- S^T[kcol][m] = sum_d K[kcol][d] * Q[m][d] ----
        f32x4 st[4];
        #pragma unroll
        for (int f = 0; f < 4; ++f) {
            const int row  = 16 * f + llo;
            const int base = row * 128;
            const int sw   = (row & 7) << 4;
            const short8 a0 = *(const short8*)(K_ + ((base + ((lhi * 16) ^ sw)) >> 1));
            const short8 a1 = *(const short8*)(K_ + ((base + ((64 + lhi * 16) ^ sw)) >> 1));
            f32x4 z; z = 0.0f;
            z     = __builtin_amdgcn_mfma_f32_16x16x32_bf16(a0, qf0, z, 0, 0, 0);
            st[f] = __builtin_amdgcn_mfma_f32_16x16x32_bf16(a1, qf1, z, 0, 0, 0);
        }

        // ---- sigmoid -> bf16, packed b64 writes: P[m][kcol 16f+lhi*4 .. +4) ----
        #pragma unroll
        for (int f = 0; f < 4; ++f) {
            const unsigned int u0 = f2bf(sigm(st[f][0]));
            const unsigned int u1 = f2bf(sigm(st[f][1]));
            const unsigned int u2 = f2bf(sigm(st[f][2]));
            const unsigned int u3 = f2bf(sigm(st[f][3]));
            u32x2 pk; pk[0] = u0 | (u1 << 16); pk[1] = u2 | (u3 << 16);
            *(u32x2*)(&Ps[(pbase + ((32 * f + lhi * 8) ^ psw)) >> 1]) = pk;
        }

        // ---- PV: O[m][d] += sum_kc P[m][kc] * VT[d][kc] ----
        const short8 pa0 = *(const short8*)(&Ps[(pbase + ((lhi * 16) ^ psw)) >> 1]);
        const short8 pa1 = *(const short8*)(&Ps[(pbase + ((64 + lhi * 16) ^ psw)) >> 1]);
        #pragma unroll
        for (int f = 0; f < 4; ++f) {
            const int row  = 16 * f + llo;
            const int base = row * 128;
            const int sw   = (row & 7) << 4;
            const short8 b0 = *(const short8*)(V_ + ((base + ((lhi * 16) ^ sw)) >> 1));
            const short8 b1 = *(const short8*)(V_ + ((base + ((64 + lhi * 16) ^ sw)) >> 1));
            oacc[f] = __builtin_amdgcn_mfma_f32_16x16x32_bf16(pa0, b0, oacc[f], 0, 0, 0);
            oacc[f] = __builtin_amdgcn_mfma_f32_16x16x32_bf16(pa1, b1, oacc[f], 0, 0, 0);
        }

        if (kt + 1 < 64) WRITET(cur ^ 1);   // fill other buffer (safe: all waves past
        __syncthreads();                    // previous barrier are done reading it)
        cur ^= 1;
    }

    // ---- epilogue: residual + scale, with layout transpose ----
    const float w = wsc[0];
    #pragma unroll
    for (int f = 0; f < 4; ++f) {
        const int d = 16 * f + llo;
        #pragma unroll
        for (int r = 0; r < 4; ++r) {
            const int mloc = wave * 16 + lhi * 4 + r;
            int idx;
            if (MODE == 0) idx = b * BHWC + d * 4096 + m0 + mloc;
            else           idx = b * BHWC + (m0 >> 6) * 4096 + d * 64 + mloc;
            xout[idx] = oacc[f][r] * w + xres[idx];
        }
    }
}

// ---------------------------------------------------------------------------
extern "C" void kernel_launch(void* const* d_in, const int* in_sizes, int n_in,
                              void* d_out, int out_size, void* d_ws, size_t ws_size,
                              hipStream_t stream) {
    const float* x    = (const float*)d_in[0];
    const float* hq_w = (const float*)d_in[1];
    const float* hq_b = (const float*)d_in[2];
    const float* hv_w = (const float*)d_in[3];
    const float* hv_b = (const float*)d_in[4];
    const float* wq_w = (const float*)d_in[5];
    const float* wq_b = (const float*)d_in[6];
    const float* wv_w = (const float*)d_in[7];
    const float* wv_b = (const float*)d_in[8];
    const float* h_wt = (const float*)d_in[9];
    const float* w_wt = (const float*)d_in[10];
    float* out = (float*)d_out;

    // workspace: Q bf16 [4][4096][64] (2MB) + V^T bf16 [4][64][4096] (2MB)
    unsigned short* Qws  = (unsigned short*)d_ws;
    unsigned short* VTws = Qws + 4 * BHWC;

    // pass 1 (height axis); x_mid lives in d_out
    proj_kernel<0><<<256, 256, 0, stream>>>(x, hq_w, hq_b, hv_w, hv_b, Qws, VTws);
    attn_kernel<0><<<256, 256, 0, stream>>>(Qws, VTws, x, h_wt, out);
    // pass 2 (width axis), in-place on d_out (read/write same element by same thread)
    proj_kernel<1><<<256, 256, 0, stream>>>(out, wq_w, wq_b, wv_w, wv_b, Qws, VTws);
    attn_kernel<1><<<256, 256, 0, stream>>>(Qws, VTws, out, w_wt, out);
}

// Round 3
// 96.367 us; speedup vs baseline: 1.7504x; 1.7504x over previous
//
#include <hip/hip_runtime.h>
#include <hip/hip_bf16.h>

// AxialAtten B=4,H=W=C=64. Two passes: Q=xW^T+b; K=Q; V=xWv^T+b;
// O = sigmoid(QK^T/8) V; x = O*scale + x (with axis transpose).
// Pass1: xh[b,n,d] = x[b*BHWC + d*4096 + n]            (n=w*64+c, d=h)
// Pass2: xw[b,n,d] = x[b*BHWC + (n>>6)*4096 + d*64 + (n&63)]  (d=w)

typedef __attribute__((ext_vector_type(8)))  short        short8;   // 8 bf16
typedef __attribute__((ext_vector_type(16))) float        f32x16;
typedef __attribute__((ext_vector_type(4)))  unsigned int u32x4;

#define BHWC (4096 * 64)

__device__ __forceinline__ unsigned short f2bf(float f) {
    union { float f; unsigned int u; } c; c.f = f;
    return (unsigned short)((c.u + 0x7FFFu + ((c.u >> 16) & 1u)) >> 16);
}
__device__ __forceinline__ float sigm(float s) {            // sigmoid(s/8)
    float e = __expf(-0.125f * s);
    return __builtin_amdgcn_rcpf(1.0f + e);
}
__device__ __forceinline__ f32x16 zero16() {
    f32x16 z;
    #pragma unroll
    for (int r = 0; r < 16; ++r) z[r] = 0.0f;
    return z;
}

// ---------------------------------------------------------------------------
// MFMA projection: Q[b][n][o] bf16 and V^T[b][o][n] bf16.
// grid 256 = 4b x 64 n-tiles, block 256 (4 waves: 2 for Q, 2 for V).
// ---------------------------------------------------------------------------
template<int MODE>
__global__ __launch_bounds__(256) void proj_kernel(
    const float* __restrict__ xsrc,
    const float* __restrict__ Wq, const float* __restrict__ Bq,
    const float* __restrict__ Wv, const float* __restrict__ Bv,
    unsigned short* __restrict__ Qo, unsigned short* __restrict__ VTo)
{
    __shared__ __align__(16) unsigned short xbf[64 * 64];      // [n][d] XOR-swizzled
    __shared__ __align__(16) unsigned short wbf[2][64 * 64];   // [o][d] XOR-swizzled
    __shared__ __align__(16) unsigned short vst[64 * 66];      // [o][n] V re-stage

    const int b = blockIdx.x >> 6, tile = blockIdx.x & 63, n0 = tile << 6;
    const int tid = threadIdx.x;
    const float* xb = xsrc + b * BHWC;

    for (int i = tid; i < 4096; i += 256) {
        const int d = i >> 6, nl = i & 63;
        float v;
        if (MODE == 0) v = xb[d * 4096 + n0 + nl];
        else           v = xb[tile * 4096 + i];          // = tile*4096 + d*64 + c
        xbf[nl * 64 + (d ^ ((nl & 7) << 3))] = f2bf(v);
        wbf[0][d * 64 + (nl ^ ((d & 7) << 3))] = f2bf(Wq[i]);
        wbf[1][d * 64 + (nl ^ ((d & 7) << 3))] = f2bf(Wv[i]);
    }
    __syncthreads();

    const int wave = tid >> 6, lane = tid & 63, l31 = lane & 31, hi = lane >> 5;
    const int mat = wave >> 1, nc = wave & 1;
    const int o = nc * 32 + l31;

    short8 bw[4];
    #pragma unroll
    for (int dc = 0; dc < 4; ++dc)
        bw[dc] = *(const short8*)&wbf[mat][o * 64 + ((dc * 16 + hi * 8) ^ ((o & 7) << 3))];

    f32x16 acc[2]; acc[0] = zero16(); acc[1] = zero16();
    #pragma unroll
    for (int dc = 0; dc < 4; ++dc) {
        #pragma unroll
        for (int mc = 0; mc < 2; ++mc) {
            const int row = mc * 32 + l31;
            const short8 a = *(const short8*)&xbf[row * 64 + ((dc * 16 + hi * 8) ^ ((row & 7) << 3))];
            acc[mc] = __builtin_amdgcn_mfma_f32_32x32x16_bf16(a, bw[dc], acc[mc], 0, 0, 0);
        }
    }
    const float bias = (mat ? Bv : Bq)[o];

    if (mat == 0) {
        unsigned short* Qb = Qo + b * BHWC;
        #pragma unroll
        for (int mc = 0; mc < 2; ++mc)
            #pragma unroll
            for (int reg = 0; reg < 16; ++reg) {
                const int n = n0 + mc * 32 + (reg & 3) + 8 * (reg >> 2) + 4 * hi;
                Qb[n * 64 + o] = f2bf(acc[mc][reg] + bias);
            }
    } else {
        #pragma unroll
        for (int mc = 0; mc < 2; ++mc)
            #pragma unroll
            for (int reg = 0; reg < 16; ++reg) {
                const int nl2 = mc * 32 + (reg & 3) + 8 * (reg >> 2) + 4 * hi;
                vst[o * 66 + nl2] = f2bf(acc[mc][reg] + bias);
            }
    }
    __syncthreads();
    {   // coalesced V^T writeback: 4 threads per o-row
        unsigned short* VTb = VTo + b * BHWC;
        const int oo = tid >> 2, seg = tid & 3;
        u32x4 t0, t1;
        #pragma unroll
        for (int j = 0; j < 4; ++j) {
            t0[j] = *(const unsigned int*)&vst[oo * 66 + seg * 16 + j * 2];
            t1[j] = *(const unsigned int*)&vst[oo * 66 + seg * 16 + 8 + j * 2];
        }
        *(u32x4*)(VTb + oo * 4096 + n0 + seg * 16)     = t0;
        *(u32x4*)(VTb + oo * 4096 + n0 + seg * 16 + 8) = t1;
    }
}

// ---------------------------------------------------------------------------
// Fused sigmoid-attention, 32x32 MFMA, P via per-wave-private LDS tile
// (round-1-proven redistribution path; no permlane/cvtpk).
// grid 256 = 4b x 64 m-tiles(64 rows); block 512 = 8 waves, wave w owns
// k-slice [w*512,(w+1)*512); partials tree-reduced via LDS; no atomics.
// ---------------------------------------------------------------------------
template<int MODE>
__global__ __launch_bounds__(512, 2) void attn_kernel(
    const unsigned short* __restrict__ Q,    // [b][4096][64] bf16 (= K)
    const unsigned short* __restrict__ VT,   // [b][64][4096] bf16
    const float* __restrict__ xres,
    const float* __restrict__ wsc,
    float* __restrict__ xout)
{
    __shared__ __align__(16) unsigned short Ps[8][64 * 64];  // per-wave P [m][k], swizzled
    __shared__ float Obuf[4][64 * 66];                       // [d][m], pad 66

    const int b = blockIdx.x >> 6, m0 = (blockIdx.x & 63) << 6;
    const int tid = threadIdx.x, wave = tid >> 6, lane = tid & 63;
    const int l31 = lane & 31, hi = lane >> 5;
    const unsigned short* Qb  = Q  + b * BHWC;
    const unsigned short* VTb = VT + b * BHWC;
    char* Pw = (char*)&Ps[wave][0];

    // Q B-fragments (held in registers all loop): B[k=d][col=m]
    short8 qf[4][2];
    #pragma unroll
    for (int dc = 0; dc < 4; ++dc)
        #pragma unroll
        for (int mc = 0; mc < 2; ++mc)
            qf[dc][mc] = *(const short8*)(Qb + (m0 + mc * 32 + l31) * 64 + dc * 16 + hi * 8);

    f32x16 acc[2][2];   // [mc][dc2] : O[64m][64d]
    acc[0][0] = zero16(); acc[0][1] = zero16();
    acc[1][0] = zero16(); acc[1][1] = zero16();

    #pragma unroll 1
    for (int i = 0; i < 8; ++i) {
        const int kbase = (wave * 8 + i) * 64;

        // V B-frags: B[k][col=d]; issue loads early (consumed in PV)
        short8 vf[4][2];
        #pragma unroll
        for (int kc = 0; kc < 4; ++kc)
            #pragma unroll
            for (int dc2 = 0; dc2 < 2; ++dc2)
                vf[kc][dc2] = *(const short8*)(VTb + (dc2 * 32 + l31) * 4096 + kbase + kc * 16 + hi * 8);

        // ---- S^T = K Q^T, sigmoid, P -> per-wave LDS tile ----
        #pragma unroll
        for (int krc = 0; krc < 2; ++krc) {
            short8 kf[4];   // K A-frags: A[row=kr][k=d]
            #pragma unroll
            for (int dc = 0; dc < 4; ++dc)
                kf[dc] = *(const short8*)(Qb + (kbase + krc * 32 + l31) * 64 + dc * 16 + hi * 8);
            #pragma unroll
            for (int mc = 0; mc < 2; ++mc) {
                f32x16 s = zero16();
                #pragma unroll
                for (int dc = 0; dc < 4; ++dc)
                    s = __builtin_amdgcn_mfma_f32_32x32x16_bf16(kf[dc], qf[dc][mc], s, 0, 0, 0);
                // lane holds S^T[kr][m]: m = mc*32+l31, kr = (reg&3)+8*(reg>>2)+4*hi
                const int m = mc * 32 + l31;
                #pragma unroll
                for (int j = 0; j < 8; ++j) {   // regs (2j,2j+1) -> consecutive kr pair
                    const unsigned int pk = (unsigned int)f2bf(sigm(s[2 * j]))
                                          | ((unsigned int)f2bf(sigm(s[2 * j + 1])) << 16);
                    const int kr = krc * 32 + 2 * (j & 1) + 8 * (j >> 1) + 4 * hi;
                    *(unsigned int*)(Pw + ((m * 128 + kr * 2) ^ ((m & 7) << 4))) = pk;
                }
            }
        }

        // ---- read P A-frags back (per-wave private: no barrier needed) ----
        short8 pf[2][4];
        #pragma unroll
        for (int mc = 0; mc < 2; ++mc) {
            const int m = mc * 32 + l31;
            #pragma unroll
            for (int kc = 0; kc < 4; ++kc)
                pf[mc][kc] = *(const short8*)(Pw + ((m * 128 + kc * 32 + hi * 16) ^ ((m & 7) << 4)));
        }

        // ---- O[m][d] += P[m][k] V[k][d] ----
        #pragma unroll
        for (int mc = 0; mc < 2; ++mc)
            #pragma unroll
            for (int dc2 = 0; dc2 < 2; ++dc2)
                #pragma unroll
                for (int kc = 0; kc < 4; ++kc)
                    acc[mc][dc2] = __builtin_amdgcn_mfma_f32_32x32x16_bf16(pf[mc][kc], vf[kc][dc2], acc[mc][dc2], 0, 0, 0);
    }

    // ---- tree-reduce the 8 wave partials through LDS ----
    if (wave < 4) {
        #pragma unroll
        for (int mc = 0; mc < 2; ++mc)
            #pragma unroll
            for (int dc2 = 0; dc2 < 2; ++dc2)
                #pragma unroll
                for (int reg = 0; reg < 16; ++reg) {
                    const int m = mc * 32 + (reg & 3) + 8 * (reg >> 2) + 4 * hi;
                    Obuf[wave][(dc2 * 32 + l31) * 66 + m] = acc[mc][dc2][reg];
                }
    }
    __syncthreads();
    if (wave >= 4) {
        float* Ob = Obuf[wave - 4];
        #pragma unroll
        for (int mc = 0; mc < 2; ++mc)
            #pragma unroll
            for (int dc2 = 0; dc2 < 2; ++dc2)
                #pragma unroll
                for (int reg = 0; reg < 16; ++reg) {
                    const int m = mc * 32 + (reg & 3) + 8 * (reg >> 2) + 4 * hi;
                    Ob[(dc2 * 32 + l31) * 66 + m] += acc[mc][dc2][reg];
                }
    }
    __syncthreads();

    // ---- epilogue: sum 4 buffers + residual, coalesced stores ----
    const float w = wsc[0];
    const int d = tid >> 3, ms = (tid & 7) << 3;
    long base;
    if (MODE == 0) base = (long)b * BHWC + d * 4096 + m0 + ms;
    else           base = (long)b * BHWC + (m0 >> 6) * 4096 + d * 64 + ms;
    #pragma unroll
    for (int j = 0; j < 8; ++j) {
        const int idx = d * 66 + ms + j;
        const float o = Obuf[0][idx] + Obuf[1][idx] + Obuf[2][idx] + Obuf[3][idx];
        xout[base + j] = o * w + xres[base + j];
    }
}

// ---------------------------------------------------------------------------
extern "C" void kernel_launch(void* const* d_in, const int* in_sizes, int n_in,
                              void* d_out, int out_size, void* d_ws, size_t ws_size,
                              hipStream_t stream) {
    const float* x    = (const float*)d_in[0];
    const float* hq_w = (const float*)d_in[1];
    const float* hq_b = (const float*)d_in[2];
    const float* hv_w = (const float*)d_in[3];
    const float* hv_b = (const float*)d_in[4];
    const float* wq_w = (const float*)d_in[5];
    const float* wq_b = (const float*)d_in[6];
    const float* wv_w = (const float*)d_in[7];
    const float* wv_b = (const float*)d_in[8];
    const float* h_wt = (const float*)d_in[9];
    const float* w_wt = (const float*)d_in[10];
    float* out = (float*)d_out;

    unsigned short* Qws  = (unsigned short*)d_ws;          // 2MB
    unsigned short* VTws = Qws + 4 * BHWC;                 // 2MB

    proj_kernel<0><<<256, 256, 0, stream>>>(x, hq_w, hq_b, hv_w, hv_b, Qws, VTws);
    attn_kernel<0><<<256, 512, 0, stream>>>(Qws, VTws, x, h_wt, out);
    proj_kernel<1><<<256, 256, 0, stream>>>(out, wq_w, wq_b, wv_w, wv_b, Qws, VTws);
    attn_kernel<1><<<256, 512, 0, stream>>>(Qws, VTws, out, w_wt, out);
}